// Round 1
// baseline (2489.968 us; speedup 1.0000x reference)
//
#include <hip/hip_runtime.h>
#include <hip/hip_bf16.h>

#define Bsz 32
#define Lsz 384
#define Dsz 512
#define Hn  16
#define DKs 32
#define SCALEF 0.17677669529663687f

// ---------------- Tiled fp32 GEMM: C = A @ W + bias ----------------
// A: [M,512] row-major, W: [512,512] row-major, M = 12288.
// mode 0: out[((b*Hn + h)*Lsz + l)*DKs + dk]  (head-major; m=b*Lsz+l, h=n>>5, dk=n&31)
// mode 1: out[m*512 + n]                      (flat)
__global__ __launch_bounds__(256) void gemm_kernel(
    const float* __restrict__ A, const float* __restrict__ W,
    const float* __restrict__ bias, float* __restrict__ out, int mode)
{
    __shared__ float As[16][68];   // [kk][m], padded to 68 floats (272B, 16B-aligned rows)
    __shared__ float Ws[16][68];   // [kk][n]

    const int tid = threadIdx.x;
    const int tx = tid & 15, ty = tid >> 4;
    const int m0 = blockIdx.x * 64, n0 = blockIdx.y * 64;

    float acc[4][4];
    #pragma unroll
    for (int i = 0; i < 4; ++i)
        #pragma unroll
        for (int j = 0; j < 4; ++j) acc[i][j] = 0.f;

    const int ra = tid >> 2, ca = tid & 3;    // A tile: 64 rows x 4 float4
    const int rb = tid >> 4, cb = tid & 15;   // W tile: 16 rows x 16 float4

    for (int k0 = 0; k0 < 512; k0 += 16) {
        float4 a4 = *(const float4*)&A[(size_t)(m0 + ra) * 512 + k0 + ca * 4];
        float4 w4 = *(const float4*)&W[(size_t)(k0 + rb) * 512 + n0 + cb * 4];
        As[ca * 4 + 0][ra] = a4.x;
        As[ca * 4 + 1][ra] = a4.y;
        As[ca * 4 + 2][ra] = a4.z;
        As[ca * 4 + 3][ra] = a4.w;
        *(float4*)&Ws[rb][cb * 4] = w4;
        __syncthreads();
        #pragma unroll
        for (int kk = 0; kk < 16; ++kk) {
            float4 av = *(const float4*)&As[kk][ty * 4];
            float4 wv = *(const float4*)&Ws[kk][tx * 4];
            float aa[4] = {av.x, av.y, av.z, av.w};
            float bb[4] = {wv.x, wv.y, wv.z, wv.w};
            #pragma unroll
            for (int i = 0; i < 4; ++i)
                #pragma unroll
                for (int j = 0; j < 4; ++j) acc[i][j] += aa[i] * bb[j];
        }
        __syncthreads();
    }

    #pragma unroll
    for (int i = 0; i < 4; ++i) {
        int m = m0 + ty * 4 + i;
        int b = m / Lsz;
        int l = m - b * Lsz;
        #pragma unroll
        for (int j = 0; j < 4; ++j) {
            int n = n0 + tx * 4 + j;
            float val = acc[i][j] + bias[n];
            if (mode == 0) {
                int h = n >> 5, dk = n & 31;
                out[((size_t)(b * Hn + h) * Lsz + l) * DKs + dk] = val;
            } else {
                out[(size_t)m * 512 + n] = val;
            }
        }
    }
}

// ---------------- Fused attention ----------------
__device__ __forceinline__ float dot32(const float* q, const float* r) {
    float a0 = 0.f, a1 = 0.f, a2 = 0.f, a3 = 0.f;
    #pragma unroll
    for (int c = 0; c < 8; ++c) {
        float4 t = *(const float4*)&r[c * 4];
        a0 += q[4 * c + 0] * t.x;
        a1 += q[4 * c + 1] * t.y;
        a2 += q[4 * c + 2] * t.z;
        a3 += q[4 * c + 3] * t.w;
    }
    return (a0 + a1) + (a2 + a3);
}

__global__ __launch_bounds__(128) void attn_kernel(
    const float* __restrict__ qg, const float* __restrict__ kg, const float* __restrict__ vg,
    const float* __restrict__ Wql, const float* __restrict__ bql,
    const float* __restrict__ Wkl, const float* __restrict__ bkl,
    float* __restrict__ ao)
{
    __shared__ float kt [128][36];   // padded: 36 floats = 144B rows (16B aligned)
    __shared__ float kLt[128][36];
    __shared__ float vt [128][36];

    const int tid = threadIdx.x;
    const int qt = blockIdx.x, h = blockIdx.y, b = blockIdx.z;
    const int l = qt * 128 + tid;                 // this thread's q-row
    const size_t hb = (size_t)(b * Hn + h) * Lsz * DKs;

    // ---- q row and qL row into registers ----
    float qreg[32], qLreg[32];
    {
        const float4* qp = (const float4*)(qg + hb + (size_t)l * DKs);
        #pragma unroll
        for (int c = 0; c < 8; ++c) {
            float4 t = qp[c];
            qreg[4 * c + 0] = t.x; qreg[4 * c + 1] = t.y;
            qreg[4 * c + 2] = t.z; qreg[4 * c + 3] = t.w;
        }
    }
    #pragma unroll
    for (int d = 0; d < 32; ++d) qLreg[d] = bql[d];
    #pragma unroll
    for (int e = 0; e < 32; ++e) {
        float qe = qreg[e];
        #pragma unroll
        for (int d = 0; d < 32; ++d) qLreg[d] += qe * Wql[e * 32 + d];
    }

    // ---- Pass A: online softmax stats for phi-scores (m1,s1) and attn-scores (m2,s2) ----
    float m1 = -1e30f, s1 = 0.f, m2 = -1e30f, s2 = 0.f;
    for (int jt = 0; jt < 3; ++jt) {
        {   // stage K tile (coalesced float4)
            const float4* src = (const float4*)(kg + hb + (size_t)jt * 128 * DKs);
            #pragma unroll
            for (int i = 0; i < 8; ++i) {
                int f = i * 128 + tid;
                *(float4*)&kt[f >> 3][(f & 7) * 4] = src[f];
            }
        }
        __syncthreads();
        {   // kL row tid = k[tid] @ Wkl + bkl
            float kr[32], kl[32];
            #pragma unroll
            for (int c = 0; c < 8; ++c) {
                float4 t = *(const float4*)&kt[tid][c * 4];
                kr[4 * c + 0] = t.x; kr[4 * c + 1] = t.y;
                kr[4 * c + 2] = t.z; kr[4 * c + 3] = t.w;
            }
            #pragma unroll
            for (int d = 0; d < 32; ++d) kl[d] = bkl[d];
            #pragma unroll
            for (int e = 0; e < 32; ++e) {
                float ke = kr[e];
                #pragma unroll
                for (int d = 0; d < 32; ++d) kl[d] += ke * Wkl[e * 32 + d];
            }
            #pragma unroll
            for (int c = 0; c < 8; ++c)
                *(float4*)&kLt[tid][c * 4] =
                    make_float4(kl[4 * c], kl[4 * c + 1], kl[4 * c + 2], kl[4 * c + 3]);
        }
        __syncthreads();
        for (int j = 0; j < 128; ++j) {
            float s1v = dot32(qLreg, &kLt[j][0]) * SCALEF;
            float s2v = dot32(qreg,  &kt [j][0]) * SCALEF;
            float mn1 = fmaxf(m1, s1v);
            s1 = s1 * __expf(m1 - mn1) + __expf(s1v - mn1);
            m1 = mn1;
            float mn2 = fmaxf(m2, s2v);
            s2 = s2 * __expf(m2 - mn2) + __expf(s2v - mn2);
            m2 = mn2;
        }
        __syncthreads();
    }

    // ---- Pass B: cumsum(phi) * softmax(scores) @ V ----
    const float inv1 = 1.f / s1, inv2 = 1.f / s2;
    float cum = 0.f;
    float oacc[32];
    #pragma unroll
    for (int d = 0; d < 32; ++d) oacc[d] = 0.f;

    for (int jt = 0; jt < 3; ++jt) {
        {   // stage K and V tiles
            const float4* srck = (const float4*)(kg + hb + (size_t)jt * 128 * DKs);
            const float4* srcv = (const float4*)(vg + hb + (size_t)jt * 128 * DKs);
            #pragma unroll
            for (int i = 0; i < 8; ++i) {
                int f = i * 128 + tid;
                *(float4*)&kt[f >> 3][(f & 7) * 4] = srck[f];
                *(float4*)&vt[f >> 3][(f & 7) * 4] = srcv[f];
            }
        }
        __syncthreads();
        {   // kL row tid
            float kr[32], kl[32];
            #pragma unroll
            for (int c = 0; c < 8; ++c) {
                float4 t = *(const float4*)&kt[tid][c * 4];
                kr[4 * c + 0] = t.x; kr[4 * c + 1] = t.y;
                kr[4 * c + 2] = t.z; kr[4 * c + 3] = t.w;
            }
            #pragma unroll
            for (int d = 0; d < 32; ++d) kl[d] = bkl[d];
            #pragma unroll
            for (int e = 0; e < 32; ++e) {
                float ke = kr[e];
                #pragma unroll
                for (int d = 0; d < 32; ++d) kl[d] += ke * Wkl[e * 32 + d];
            }
            #pragma unroll
            for (int c = 0; c < 8; ++c)
                *(float4*)&kLt[tid][c * 4] =
                    make_float4(kl[4 * c], kl[4 * c + 1], kl[4 * c + 2], kl[4 * c + 3]);
        }
        __syncthreads();
        for (int j = 0; j < 128; ++j) {
            float s1v = dot32(qLreg, &kLt[j][0]) * SCALEF;
            float s2v = dot32(qreg,  &kt [j][0]) * SCALEF;
            cum += __expf(s1v - m1) * inv1;                 // inclusive cumsum of phi
            float aw = __expf(s2v - m2) * inv2 * cum;       // softmax * m_s
            #pragma unroll
            for (int c = 0; c < 8; ++c) {
                float4 v4 = *(const float4*)&vt[j][c * 4];
                oacc[4 * c + 0] += aw * v4.x;
                oacc[4 * c + 1] += aw * v4.y;
                oacc[4 * c + 2] += aw * v4.z;
                oacc[4 * c + 3] += aw * v4.w;
            }
        }
        __syncthreads();
    }

    // write [b, l, h*32 + d]
    float* op = ao + ((size_t)(b * Lsz) + l) * Dsz + h * DKs;
    #pragma unroll
    for (int c = 0; c < 8; ++c)
        *(float4*)&op[c * 4] =
            make_float4(oacc[4 * c], oacc[4 * c + 1], oacc[4 * c + 2], oacc[4 * c + 3]);
}

extern "C" void kernel_launch(void* const* d_in, const int* in_sizes, int n_in,
                              void* d_out, int out_size, void* d_ws, size_t ws_size,
                              hipStream_t stream) {
    const float* Q   = (const float*)d_in[0];
    const float* Wq  = (const float*)d_in[1];
    const float* bq  = (const float*)d_in[2];
    const float* Wk  = (const float*)d_in[3];
    const float* bk  = (const float*)d_in[4];
    const float* Wv  = (const float*)d_in[5];
    const float* bv  = (const float*)d_in[6];
    const float* Wql = (const float*)d_in[7];
    const float* bql = (const float*)d_in[8];
    const float* Wkl = (const float*)d_in[9];
    const float* bkl = (const float*)d_in[10];
    const float* Wo  = (const float*)d_in[11];
    const float* bo  = (const float*)d_in[12];
    // d_in[13] = triu: unused — phi @ triu == inclusive cumsum(phi, axis=-1)

    const size_t NTOK = (size_t)Bsz * Lsz * Dsz;   // 6291456 elements
    float* q_ws = (float*)d_ws;
    float* k_ws = q_ws + NTOK;
    float* v_ws = k_ws + NTOK;
    float* ao   = v_ws + NTOK;                     // total 4*NTOK*4B = 100.7 MB

    dim3 gg(192, 8);
    gemm_kernel<<<gg, 256, 0, stream>>>(Q, Wq, bq, q_ws, 0);
    gemm_kernel<<<gg, 256, 0, stream>>>(Q, Wk, bk, k_ws, 0);
    gemm_kernel<<<gg, 256, 0, stream>>>(Q, Wv, bv, v_ws, 0);
    attn_kernel<<<dim3(3, Hn, Bsz), 128, 0, stream>>>(q_ws, k_ws, v_ws,
                                                      Wql, bql, Wkl, bkl, ao);
    gemm_kernel<<<gg, 256, 0, stream>>>(ao, Wo, bo, (float*)d_out, 1);
}

// Round 2
// 467.909 us; speedup vs baseline: 5.3215x; 5.3215x over previous
//
#include <hip/hip_runtime.h>
#include <hip/hip_bf16.h>

#define Bsz 32
#define Lsz 384
#define Dsz 512
#define Hn  16
#define DKs 32
#define SCALEF 0.17677669529663687f

typedef __attribute__((ext_vector_type(8))) short bf16x8;
typedef __attribute__((ext_vector_type(4))) float f32x4;

__device__ __forceinline__ unsigned pk2(float a, float b) {
    union { __hip_bfloat16 h; unsigned short u; } ca, cb;
    ca.h = __float2bfloat16(a);
    cb.h = __float2bfloat16(b);
    return (unsigned)ca.u | ((unsigned)cb.u << 16);
}

// ---------------- Tiled fp32 GEMM: C = A @ W + bias ----------------
// A: [M,512] row-major fp32, W: [512,512] row-major fp32, M = 12288.
// mode 0: bf16 head-major [bh][l][dk], value *= SCALEF   (q, pre-scaled)
// mode 1: bf16 head-major [bh][l][dk]                    (k)
// mode 2: bf16 transposed [bh][dk][l]                    (vT)
// mode 3: fp32 flat [m][n]                               (final out)
__global__ __launch_bounds__(256) void gemm_kernel(
    const float* __restrict__ A, const float* __restrict__ W,
    const float* __restrict__ bias, void* __restrict__ outv, int mode)
{
    __shared__ float As[16][68];
    __shared__ float Ws[16][68];

    const int tid = threadIdx.x;
    const int tx = tid & 15, ty = tid >> 4;
    const int m0 = blockIdx.x * 64, n0 = blockIdx.y * 64;

    float acc[4][4];
    #pragma unroll
    for (int i = 0; i < 4; ++i)
        #pragma unroll
        for (int j = 0; j < 4; ++j) acc[i][j] = 0.f;

    const int ra = tid >> 2, ca = tid & 3;
    const int rb = tid >> 4, cb = tid & 15;

    for (int k0 = 0; k0 < 512; k0 += 16) {
        float4 a4 = *(const float4*)&A[(size_t)(m0 + ra) * 512 + k0 + ca * 4];
        float4 w4 = *(const float4*)&W[(size_t)(k0 + rb) * 512 + n0 + cb * 4];
        As[ca * 4 + 0][ra] = a4.x;
        As[ca * 4 + 1][ra] = a4.y;
        As[ca * 4 + 2][ra] = a4.z;
        As[ca * 4 + 3][ra] = a4.w;
        *(float4*)&Ws[rb][cb * 4] = w4;
        __syncthreads();
        #pragma unroll
        for (int kk = 0; kk < 16; ++kk) {
            float4 av = *(const float4*)&As[kk][ty * 4];
            float4 wv = *(const float4*)&Ws[kk][tx * 4];
            float aa[4] = {av.x, av.y, av.z, av.w};
            float bb[4] = {wv.x, wv.y, wv.z, wv.w};
            #pragma unroll
            for (int i = 0; i < 4; ++i)
                #pragma unroll
                for (int j = 0; j < 4; ++j) acc[i][j] += aa[i] * bb[j];
        }
        __syncthreads();
    }

    const int bb = m0 / Lsz;                 // 64 | 384 -> whole block same b
    const int l0 = m0 - bb * Lsz + ty * 4;

    if (mode <= 1) {
        const float sc = (mode == 0) ? SCALEF : 1.f;
        unsigned short* o = (unsigned short*)outv;
        const int n = n0 + tx * 4, hh = n >> 5, dk = n & 31;
        #pragma unroll
        for (int i = 0; i < 4; ++i) {
            union { __hip_bfloat16 h; unsigned short u; } c[4];
            #pragma unroll
            for (int j = 0; j < 4; ++j)
                c[j].h = __float2bfloat16((acc[i][j] + bias[n + j]) * sc);
            *(ushort4*)(o + ((size_t)(bb * Hn + hh) * Lsz + l0 + i) * DKs + dk) =
                make_ushort4(c[0].u, c[1].u, c[2].u, c[3].u);
        }
    } else if (mode == 2) {
        unsigned short* o = (unsigned short*)outv;
        #pragma unroll
        for (int j = 0; j < 4; ++j) {
            int n = n0 + tx * 4 + j, hh = n >> 5, dk = n & 31;
            union { __hip_bfloat16 h; unsigned short u; } c[4];
            #pragma unroll
            for (int i = 0; i < 4; ++i)
                c[i].h = __float2bfloat16(acc[i][j] + bias[n]);
            *(ushort4*)(o + ((size_t)(bb * Hn + hh) * DKs + dk) * Lsz + l0) =
                make_ushort4(c[0].u, c[1].u, c[2].u, c[3].u);
        }
    } else {
        float* o = (float*)outv;
        #pragma unroll
        for (int i = 0; i < 4; ++i) {
            int m = m0 + ty * 4 + i;
            #pragma unroll
            for (int j = 0; j < 4; ++j) {
                int n = n0 + tx * 4 + j;
                o[(size_t)m * 512 + n] = acc[i][j] + bias[n];
            }
        }
    }
}

// ---------------- Per-head L-projection: dst = src @ W32 + bscale*b ----------------
// src/dst: bf16 planes [BH][L][32] flat rows. W: [32][32] fp32.
__global__ __launch_bounds__(256) void lproj_kernel(
    const unsigned short* __restrict__ src, const float* __restrict__ W,
    const float* __restrict__ bias, unsigned short* __restrict__ dst, float bscale)
{
    __shared__ float Ws[32][33];
    __shared__ float bs[32];
    const int tid = threadIdx.x;
    {
        // 1024 weights, 256 threads, 4 each
        #pragma unroll
        for (int t = 0; t < 4; ++t) {
            int idx = tid * 4 + t;
            Ws[idx >> 5][idx & 31] = W[idx];
        }
        if (tid < 32) bs[tid] = bias[tid] * bscale;
    }
    __syncthreads();

    const size_t row = (size_t)blockIdx.x * 256 + tid;   // 196608 rows total
    const unsigned short* sp = src + row * 32;
    float x[32];
    #pragma unroll
    for (int c = 0; c < 4; ++c) {
        uint4 u = *(const uint4*)(sp + c * 8);
        unsigned uu[4] = {u.x, u.y, u.z, u.w};
        #pragma unroll
        for (int wi = 0; wi < 4; ++wi) {
            x[c * 8 + 2 * wi + 0] = __uint_as_float(uu[wi] << 16);
            x[c * 8 + 2 * wi + 1] = __uint_as_float(uu[wi] & 0xffff0000u);
        }
    }
    float y[32];
    #pragma unroll
    for (int d = 0; d < 32; ++d) y[d] = bs[d];
    #pragma unroll
    for (int e = 0; e < 32; ++e) {
        float xe = x[e];
        #pragma unroll
        for (int d = 0; d < 32; ++d) y[d] += xe * Ws[e][d];
    }
    unsigned short* dp = dst + row * 32;
    #pragma unroll
    for (int c = 0; c < 4; ++c) {
        unsigned uu[4];
        #pragma unroll
        for (int wi = 0; wi < 4; ++wi)
            uu[wi] = pk2(y[c * 8 + 2 * wi], y[c * 8 + 2 * wi + 1]);
        *(uint4*)(dp + c * 8) = make_uint4(uu[0], uu[1], uu[2], uu[3]);
    }
}

// ---------------- Fused MFMA attention ----------------
// S^T = mfma(K_tile, Q^T)  (16 keys x 16 q, K=32=head dim)
// C layout (m89): col = lane&15, row = 4*(lane>>4) + reg
// A/B frag: row/col = lane&15, k = 8*(lane>>4) + e
__global__ __launch_bounds__(256) void attn_mfma(
    const unsigned short* __restrict__ qs, const unsigned short* __restrict__ kp,
    const unsigned short* __restrict__ qLp, const unsigned short* __restrict__ kLp,
    const unsigned short* __restrict__ vT, float* __restrict__ ao)
{
    const int lane = threadIdx.x & 63, w = threadIdx.x >> 6;
    const int r16 = lane & 15, qd = lane >> 4;
    const int h = blockIdx.y, b = blockIdx.z;
    const size_t bh = (size_t)(b * Hn + h);
    const int q0 = blockIdx.x * 128 + w * 32;

    const unsigned short* qb  = qs  + bh * (Lsz * DKs);
    const unsigned short* kb  = kp  + bh * (Lsz * DKs);
    const unsigned short* qLb = qLp + bh * (Lsz * DKs);
    const unsigned short* kLb = kLp + bh * (Lsz * DKs);
    const unsigned short* vb  = vT  + bh * (DKs * Lsz);

    bf16x8 qf[2], qLf[2];
    #pragma unroll
    for (int s = 0; s < 2; ++s) {
        qf[s]  = *(const bf16x8*)(qb  + (q0 + 16 * s + r16) * DKs + 8 * qd);
        qLf[s] = *(const bf16x8*)(qLb + (q0 + 16 * s + r16) * DKs + 8 * qd);
    }

    f32x4 o[2][2];
    #pragma unroll
    for (int s = 0; s < 2; ++s)
        #pragma unroll
        for (int dt = 0; dt < 2; ++dt) o[s][dt] = (f32x4){0.f, 0.f, 0.f, 0.f};
    float s1t[2] = {0.f, 0.f}, s2t[2] = {0.f, 0.f}, carry[2] = {0.f, 0.f};

    for (int k0 = 0; k0 < Lsz; k0 += 32) {
        bf16x8 kA  = *(const bf16x8*)(kb  + (k0 + r16) * DKs + 8 * qd);
        bf16x8 kB  = *(const bf16x8*)(kb  + (k0 + 16 + r16) * DKs + 8 * qd);
        bf16x8 kLA = *(const bf16x8*)(kLb + (k0 + r16) * DKs + 8 * qd);
        bf16x8 kLB = *(const bf16x8*)(kLb + (k0 + 16 + r16) * DKs + 8 * qd);
        bf16x8 vf0 = *(const bf16x8*)(vb + (r16) * Lsz + k0 + 8 * qd);
        bf16x8 vf1 = *(const bf16x8*)(vb + (16 + r16) * Lsz + k0 + 8 * qd);

        #pragma unroll
        for (int s = 0; s < 2; ++s) {
            const f32x4 z = {0.f, 0.f, 0.f, 0.f};
            f32x4 S1A = __builtin_amdgcn_mfma_f32_16x16x32_bf16(kLA, qLf[s], z, 0, 0, 0);
            f32x4 S1B = __builtin_amdgcn_mfma_f32_16x16x32_bf16(kLB, qLf[s], z, 0, 0, 0);
            f32x4 S2A = __builtin_amdgcn_mfma_f32_16x16x32_bf16(kA,  qf[s],  z, 0, 0, 0);
            f32x4 S2B = __builtin_amdgcn_mfma_f32_16x16x32_bf16(kB,  qf[s],  z, 0, 0, 0);

            float e1A[4], e1B[4], e2A[4], e2B[4];
            #pragma unroll
            for (int r = 0; r < 4; ++r) {
                e1A[r] = __expf(S1A[r]);
                e1B[r] = __expf(S1B[r]);
                e2A[r] = __expf(S2A[r]);
                e2B[r] = __expf(S2B[r]);
            }
            s1t[s] += (e1A[0] + e1A[1] + e1A[2] + e1A[3]) + (e1B[0] + e1B[1] + e1B[2] + e1B[3]);
            s2t[s] += (e2A[0] + e2A[1] + e2A[2] + e2A[3]) + (e2B[0] + e2B[1] + e2B[2] + e2B[3]);

            // --- inclusive cumsum of e1 over keys (tile A then tile B) ---
            float pA0 = e1A[0], pA1 = pA0 + e1A[1], pA2 = pA1 + e1A[2], pA3 = pA2 + e1A[3];
            float Tn = __shfl_xor(pA3, 16);
            float pr = pA3 + Tn;
            float Tp = __shfl_xor(pr, 32);
            float baseA = carry[s] + ((qd & 1) ? Tn : 0.f) + ((qd & 2) ? Tp : 0.f);
            float cA0 = baseA + pA0, cA1 = baseA + pA1, cA2 = baseA + pA2, cA3 = baseA + pA3;
            carry[s] += pr + Tp;

            float pB0 = e1B[0], pB1 = pB0 + e1B[1], pB2 = pB1 + e1B[2], pB3 = pB2 + e1B[3];
            float TnB = __shfl_xor(pB3, 16);
            float prB = pB3 + TnB;
            float TpB = __shfl_xor(prB, 32);
            float baseB = carry[s] + ((qd & 1) ? TnB : 0.f) + ((qd & 2) ? TpB : 0.f);
            float cB0 = baseB + pB0, cB1 = baseB + pB1, cB2 = baseB + pB2, cB3 = baseB + pB3;
            carry[s] += prB + TpB;

            // --- P = e2 * cum, pack to bf16, re-layout to B-fragment ---
            unsigned wA0 = pk2(e2A[0] * cA0, e2A[1] * cA1);
            unsigned wA1 = pk2(e2A[2] * cA2, e2A[3] * cA3);
            unsigned wB0 = pk2(e2B[0] * cB0, e2B[1] * cB1);
            unsigned wB1 = pk2(e2B[2] * cB2, e2B[3] * cB3);

            int sl1 = r16 + ((qd & 1) ? 32 : 0);
            int sl2 = sl1 + 16;
            int a0s1 = __shfl((int)wA0, sl1), a1s1 = __shfl((int)wA1, sl1);
            int b0s1 = __shfl((int)wB0, sl1), b1s1 = __shfl((int)wB1, sl1);
            int a0s2 = __shfl((int)wA0, sl2), a1s2 = __shfl((int)wA1, sl2);
            int b0s2 = __shfl((int)wB0, sl2), b1s2 = __shfl((int)wB1, sl2);
            bool loq = (qd < 2);
            union { int i[4]; bf16x8 v; } pu;
            pu.i[0] = loq ? a0s1 : b0s1;
            pu.i[1] = loq ? a1s1 : b1s1;
            pu.i[2] = loq ? a0s2 : b0s2;
            pu.i[3] = loq ? a1s2 : b1s2;

            o[s][0] = __builtin_amdgcn_mfma_f32_16x16x32_bf16(vf0, pu.v, o[s][0], 0, 0, 0);
            o[s][1] = __builtin_amdgcn_mfma_f32_16x16x32_bf16(vf1, pu.v, o[s][1], 0, 0, 0);
        }
    }

    #pragma unroll
    for (int s = 0; s < 2; ++s) {
        float st1 = s1t[s] + __shfl_xor(s1t[s], 16);
        st1 += __shfl_xor(st1, 32);
        float st2 = s2t[s] + __shfl_xor(s2t[s], 16);
        st2 += __shfl_xor(st2, 32);
        float nm = 1.f / (st1 * st2);
        const int l = q0 + 16 * s + r16;
        float* op = ao + ((size_t)(b * Lsz) + l) * Dsz + h * DKs;
        #pragma unroll
        for (int dt = 0; dt < 2; ++dt) {
            f32x4 ov = o[s][dt];
            *(float4*)(op + 16 * dt + 4 * qd) =
                make_float4(ov[0] * nm, ov[1] * nm, ov[2] * nm, ov[3] * nm);
        }
    }
}

extern "C" void kernel_launch(void* const* d_in, const int* in_sizes, int n_in,
                              void* d_out, int out_size, void* d_ws, size_t ws_size,
                              hipStream_t stream) {
    const float* Q   = (const float*)d_in[0];
    const float* Wq  = (const float*)d_in[1];
    const float* bq  = (const float*)d_in[2];
    const float* Wk  = (const float*)d_in[3];
    const float* bk  = (const float*)d_in[4];
    const float* Wv  = (const float*)d_in[5];
    const float* bv  = (const float*)d_in[6];
    const float* Wql = (const float*)d_in[7];
    const float* bql = (const float*)d_in[8];
    const float* Wkl = (const float*)d_in[9];
    const float* bkl = (const float*)d_in[10];
    const float* Wo  = (const float*)d_in[11];
    const float* bo  = (const float*)d_in[12];
    // d_in[13] = triu: unused — phi @ triu == inclusive cumsum(phi, axis=-1)

    const size_t PLANE = (size_t)Bsz * Hn * Lsz * DKs;   // 6291456 elements
    char* ws = (char*)d_ws;
    unsigned short* qs_p  = (unsigned short*)(ws);                    // bf16, pre-scaled
    unsigned short* k_p   = (unsigned short*)(ws + 2 * PLANE);
    unsigned short* qL_p  = (unsigned short*)(ws + 4 * PLANE);
    unsigned short* kL_p  = (unsigned short*)(ws + 6 * PLANE);
    unsigned short* vT_p  = (unsigned short*)(ws + 8 * PLANE);
    float*          ao    = (float*)        (ws + 10 * PLANE);        // fp32, 25.2 MB

    dim3 gg(192, 8);
    gemm_kernel<<<gg, 256, 0, stream>>>(Q, Wq, bq, qs_p, 0);
    gemm_kernel<<<gg, 256, 0, stream>>>(Q, Wk, bk, k_p, 1);
    gemm_kernel<<<gg, 256, 0, stream>>>(Q, Wv, bv, vT_p, 2);
    lproj_kernel<<<768, 256, 0, stream>>>(qs_p, Wql, bql, qL_p, SCALEF);
    lproj_kernel<<<768, 256, 0, stream>>>(k_p,  Wkl, bkl, kL_p, 1.f);
    attn_mfma<<<dim3(3, Hn, Bsz), 256, 0, stream>>>(qs_p, k_p, qL_p, kL_p, vT_p, ao);
    gemm_kernel<<<gg, 256, 0, stream>>>(ao, Wo, bo, d_out, 3);
}

// Round 3
// 151.203 us; speedup vs baseline: 16.4678x; 3.0946x over previous
//
#include <hip/hip_runtime.h>
#include <hip/hip_bf16.h>

#define Bsz 32
#define Lsz 384
#define Dsz 512
#define Hn  16
#define DKs 32
#define SCALEF 0.17677669529663687f

typedef __attribute__((ext_vector_type(8))) short bf16x8;
typedef __attribute__((ext_vector_type(4))) float f32x4;

__device__ __forceinline__ unsigned pk2(float a, float b) {
    union { __hip_bfloat16 h; unsigned short u; } ca, cb;
    ca.h = __float2bfloat16(a);
    cb.h = __float2bfloat16(b);
    return (unsigned)ca.u | ((unsigned)cb.u << 16);
}
__device__ __forceinline__ unsigned short bfbits(float a) {
    union { __hip_bfloat16 h; unsigned short u; } c;
    c.h = __float2bfloat16(a);
    return c.u;
}
__device__ __forceinline__ void gload_lds16(const void* g, void* l) {
    __builtin_amdgcn_global_load_lds((const __attribute__((address_space(1))) void*)g,
                                     (__attribute__((address_space(3))) void*)l, 16, 0, 0);
}

// ---------------- Q fp32 -> bf16 ----------------
__global__ __launch_bounds__(256) void convq_kernel(
    const float* __restrict__ src, unsigned short* __restrict__ dst)
{
    size_t i = ((size_t)blockIdx.x * 256 + threadIdx.x) * 8;
    float4 a = *(const float4*)(src + i);
    float4 b = *(const float4*)(src + i + 4);
    *(uint4*)(dst + i) = make_uint4(pk2(a.x, a.y), pk2(a.z, a.w),
                                    pk2(b.x, b.y), pk2(b.z, b.w));
}

// ---------------- W [512][512] fp32 -> W^T bf16 [n][k] ----------------
__global__ __launch_bounds__(256) void wtrans_kernel(
    const float* __restrict__ W0, const float* __restrict__ W1,
    const float* __restrict__ W2, const float* __restrict__ W3,
    unsigned short* __restrict__ dst)
{
    const float* W = (blockIdx.z == 0) ? W0 : (blockIdx.z == 1) ? W1
                   : (blockIdx.z == 2) ? W2 : W3;
    unsigned short* out = dst + (size_t)blockIdx.z * 512 * 512;
    __shared__ float Ls[64][65];
    const int tid = threadIdx.x;
    const int k0 = blockIdx.x * 64, n0 = blockIdx.y * 64;
    #pragma unroll
    for (int i = 0; i < 4; ++i) {
        int c = i * 256 + tid;
        int r = c >> 4, c4 = c & 15;
        float4 v = *(const float4*)&W[(size_t)(k0 + r) * 512 + n0 + c4 * 4];
        Ls[r][c4 * 4 + 0] = v.x; Ls[r][c4 * 4 + 1] = v.y;
        Ls[r][c4 * 4 + 2] = v.z; Ls[r][c4 * 4 + 3] = v.w;
    }
    __syncthreads();
    #pragma unroll
    for (int i = 0; i < 2; ++i) {
        int c = i * 256 + tid;
        int n = c >> 3, kc = c & 7;
        unsigned u[4];
        #pragma unroll
        for (int p = 0; p < 4; ++p)
            u[p] = pk2(Ls[kc * 8 + 2 * p][n], Ls[kc * 8 + 2 * p + 1][n]);
        *(uint4*)&out[(size_t)(n0 + n) * 512 + k0 + kc * 8] =
            make_uint4(u[0], u[1], u[2], u[3]);
    }
}

// ---------------- bf16 MFMA GEMM: C = A @ W + bias, M=12288, N=512, K=512 ----------------
// A bf16 [M][512], WT bf16 [n][k]. BM=128, BN=64, BK=64, 256 thr (2x2 waves).
// MODE 0: q  -> bf16 [bh][l][dk], *SCALEF
// MODE 1: k  -> bf16 [bh][l][dk]
// MODE 2: vT -> bf16 [bh][dk][l]   (computes C^T via operand swap)
// MODE 3: fp32 flat [m][512]
template <int MODE>
__global__ __launch_bounds__(256) void mm_kernel(
    const unsigned short* __restrict__ A, const unsigned short* __restrict__ WT,
    const float* __restrict__ bias, void* __restrict__ outv)
{
    __shared__ __align__(16) unsigned short Asm[128 * 64];
    __shared__ __align__(16) unsigned short Bsm[64 * 64];

    const int tid = threadIdx.x, lane = tid & 63, w = tid >> 6;
    const int r16 = lane & 15, qd = lane >> 4;
    const int wm = w >> 1, wn = w & 1;

    // XCD-chunked swizzle: 768 blocks = 8 XCDs x (12 m-tiles x 8 n-tiles)
    const int bid = blockIdx.x;
    const int xcd = bid & 7, loc = bid >> 3;
    const int mt = xcd * 12 + (loc >> 3);
    const int nt = loc & 7;
    const int m0 = mt * 128, n0 = nt * 64;

    f32x4 acc[4][2];
    #pragma unroll
    for (int mi = 0; mi < 4; ++mi)
        #pragma unroll
        for (int ni = 0; ni < 2; ++ni) acc[mi][ni] = (f32x4){0.f, 0.f, 0.f, 0.f};

    for (int k0 = 0; k0 < 512; k0 += 64) {
        // stage A (1024 chunks of 16B) and B (512 chunks), swizzled source
        #pragma unroll
        for (int i = 0; i < 4; ++i) {
            int c = i * 256 + tid;
            int r = c >> 3, sl = c & 7;
            int gc = (sl ^ (r & 7)) * 8;
            gload_lds16(A + ((size_t)(m0 + r) * 512 + k0 + gc),
                        &Asm[(i * 256 + w * 64) * 8]);
            if (i < 2)
                gload_lds16(WT + ((size_t)(n0 + r) * 512 + k0 + gc),
                            &Bsm[(i * 256 + w * 64) * 8]);
        }
        __syncthreads();

        bf16x8 af[4][2], bfr[2][2];
        #pragma unroll
        for (int mi = 0; mi < 4; ++mi) {
            int row = wm * 64 + mi * 16 + r16;
            #pragma unroll
            for (int ks = 0; ks < 2; ++ks) {
                int sl = (ks * 4 + qd) ^ (row & 7);
                af[mi][ks] = *(const bf16x8*)&Asm[row * 64 + sl * 8];
            }
        }
        #pragma unroll
        for (int ni = 0; ni < 2; ++ni) {
            int row = wn * 32 + ni * 16 + r16;
            #pragma unroll
            for (int ks = 0; ks < 2; ++ks) {
                int sl = (ks * 4 + qd) ^ (row & 7);
                bfr[ni][ks] = *(const bf16x8*)&Bsm[row * 64 + sl * 8];
            }
        }
        #pragma unroll
        for (int ks = 0; ks < 2; ++ks)
            #pragma unroll
            for (int mi = 0; mi < 4; ++mi)
                #pragma unroll
                for (int ni = 0; ni < 2; ++ni) {
                    if (MODE == 2)
                        acc[mi][ni] = __builtin_amdgcn_mfma_f32_16x16x32_bf16(
                            bfr[ni][ks], af[mi][ks], acc[mi][ni], 0, 0, 0);
                    else
                        acc[mi][ni] = __builtin_amdgcn_mfma_f32_16x16x32_bf16(
                            af[mi][ks], bfr[ni][ks], acc[mi][ni], 0, 0, 0);
                }
        __syncthreads();
    }

    const int b = m0 / Lsz;
    const int l0 = m0 - b * Lsz;

    if (MODE <= 1) {
        unsigned short* o = (unsigned short*)outv;
        const float sc = (MODE == 0) ? SCALEF : 1.f;
        #pragma unroll
        for (int ni = 0; ni < 2; ++ni) {
            int n = n0 + wn * 32 + ni * 16 + r16;
            float bv_ = bias[n];
            int hh = n >> 5, dk = n & 31;
            size_t base = ((size_t)(b * Hn + hh) * Lsz) * DKs + dk;
            #pragma unroll
            for (int mi = 0; mi < 4; ++mi)
                #pragma unroll
                for (int rr = 0; rr < 4; ++rr) {
                    int l = l0 + wm * 64 + mi * 16 + qd * 4 + rr;
                    o[base + (size_t)l * DKs] = bfbits((acc[mi][ni][rr] + bv_) * sc);
                }
        }
    } else if (MODE == 2) {
        unsigned short* o = (unsigned short*)outv;
        #pragma unroll
        for (int ni = 0; ni < 2; ++ni)
            #pragma unroll
            for (int rr = 0; rr < 4; ++rr) {
                int n = n0 + wn * 32 + ni * 16 + qd * 4 + rr;
                float bv_ = bias[n];
                int hh = n >> 5, dk = n & 31;
                size_t base = ((size_t)(b * Hn + hh) * DKs + dk) * Lsz + l0;
                #pragma unroll
                for (int mi = 0; mi < 4; ++mi) {
                    int lofs = wm * 64 + mi * 16 + r16;
                    o[base + lofs] = bfbits(acc[mi][ni][rr] + bv_);
                }
            }
    } else {
        float* o = (float*)outv;
        #pragma unroll
        for (int ni = 0; ni < 2; ++ni) {
            int n = n0 + wn * 32 + ni * 16 + r16;
            float bv_ = bias[n];
            #pragma unroll
            for (int mi = 0; mi < 4; ++mi)
                #pragma unroll
                for (int rr = 0; rr < 4; ++rr) {
                    int m = m0 + wm * 64 + mi * 16 + qd * 4 + rr;
                    o[(size_t)m * 512 + n] = acc[mi][ni][rr] + bv_;
                }
        }
    }
}

// ---------------- Per-head L-projection: dst = src @ W32 + bscale*b ----------------
__global__ __launch_bounds__(256) void lproj_kernel(
    const unsigned short* __restrict__ src, const float* __restrict__ W,
    const float* __restrict__ bias, unsigned short* __restrict__ dst, float bscale)
{
    __shared__ float Ws[32][33];
    __shared__ float bs[32];
    const int tid = threadIdx.x;
    {
        #pragma unroll
        for (int t = 0; t < 4; ++t) {
            int idx = tid * 4 + t;
            Ws[idx >> 5][idx & 31] = W[idx];
        }
        if (tid < 32) bs[tid] = bias[tid] * bscale;
    }
    __syncthreads();

    const size_t row = (size_t)blockIdx.x * 256 + tid;
    const unsigned short* sp = src + row * 32;
    float x[32];
    #pragma unroll
    for (int c = 0; c < 4; ++c) {
        uint4 u = *(const uint4*)(sp + c * 8);
        unsigned uu[4] = {u.x, u.y, u.z, u.w};
        #pragma unroll
        for (int wi = 0; wi < 4; ++wi) {
            x[c * 8 + 2 * wi + 0] = __uint_as_float(uu[wi] << 16);
            x[c * 8 + 2 * wi + 1] = __uint_as_float(uu[wi] & 0xffff0000u);
        }
    }
    float y[32];
    #pragma unroll
    for (int d = 0; d < 32; ++d) y[d] = bs[d];
    #pragma unroll
    for (int e = 0; e < 32; ++e) {
        float xe = x[e];
        #pragma unroll
        for (int d = 0; d < 32; ++d) y[d] += xe * Ws[e][d];
    }
    unsigned short* dp = dst + row * 32;
    #pragma unroll
    for (int c = 0; c < 4; ++c) {
        unsigned uu[4];
        #pragma unroll
        for (int wi = 0; wi < 4; ++wi)
            uu[wi] = pk2(y[c * 8 + 2 * wi], y[c * 8 + 2 * wi + 1]);
        *(uint4*)(dp + c * 8) = make_uint4(uu[0], uu[1], uu[2], uu[3]);
    }
}

// ---------------- Fused MFMA attention (ao written bf16) ----------------
__global__ __launch_bounds__(256) void attn_mfma(
    const unsigned short* __restrict__ qs, const unsigned short* __restrict__ kp,
    const unsigned short* __restrict__ qLp, const unsigned short* __restrict__ kLp,
    const unsigned short* __restrict__ vT, unsigned short* __restrict__ ao)
{
    const int lane = threadIdx.x & 63, w = threadIdx.x >> 6;
    const int r16 = lane & 15, qd = lane >> 4;
    const int h = blockIdx.y, b = blockIdx.z;
    const size_t bh = (size_t)(b * Hn + h);
    const int q0 = blockIdx.x * 128 + w * 32;

    const unsigned short* qb  = qs  + bh * (Lsz * DKs);
    const unsigned short* kb  = kp  + bh * (Lsz * DKs);
    const unsigned short* qLb = qLp + bh * (Lsz * DKs);
    const unsigned short* kLb = kLp + bh * (Lsz * DKs);
    const unsigned short* vb  = vT  + bh * (DKs * Lsz);

    bf16x8 qf[2], qLf[2];
    #pragma unroll
    for (int s = 0; s < 2; ++s) {
        qf[s]  = *(const bf16x8*)(qb  + (q0 + 16 * s + r16) * DKs + 8 * qd);
        qLf[s] = *(const bf16x8*)(qLb + (q0 + 16 * s + r16) * DKs + 8 * qd);
    }

    f32x4 o[2][2];
    #pragma unroll
    for (int s = 0; s < 2; ++s)
        #pragma unroll
        for (int dt = 0; dt < 2; ++dt) o[s][dt] = (f32x4){0.f, 0.f, 0.f, 0.f};
    float s1t[2] = {0.f, 0.f}, s2t[2] = {0.f, 0.f}, carry[2] = {0.f, 0.f};

    for (int k0 = 0; k0 < Lsz; k0 += 32) {
        bf16x8 kA  = *(const bf16x8*)(kb  + (k0 + r16) * DKs + 8 * qd);
        bf16x8 kB  = *(const bf16x8*)(kb  + (k0 + 16 + r16) * DKs + 8 * qd);
        bf16x8 kLA = *(const bf16x8*)(kLb + (k0 + r16) * DKs + 8 * qd);
        bf16x8 kLB = *(const bf16x8*)(kLb + (k0 + 16 + r16) * DKs + 8 * qd);
        bf16x8 vf0 = *(const bf16x8*)(vb + (r16) * Lsz + k0 + 8 * qd);
        bf16x8 vf1 = *(const bf16x8*)(vb + (16 + r16) * Lsz + k0 + 8 * qd);

        #pragma unroll
        for (int s = 0; s < 2; ++s) {
            const f32x4 z = {0.f, 0.f, 0.f, 0.f};
            f32x4 S1A = __builtin_amdgcn_mfma_f32_16x16x32_bf16(kLA, qLf[s], z, 0, 0, 0);
            f32x4 S1B = __builtin_amdgcn_mfma_f32_16x16x32_bf16(kLB, qLf[s], z, 0, 0, 0);
            f32x4 S2A = __builtin_amdgcn_mfma_f32_16x16x32_bf16(kA,  qf[s],  z, 0, 0, 0);
            f32x4 S2B = __builtin_amdgcn_mfma_f32_16x16x32_bf16(kB,  qf[s],  z, 0, 0, 0);

            float e1A[4], e1B[4], e2A[4], e2B[4];
            #pragma unroll
            for (int r = 0; r < 4; ++r) {
                e1A[r] = __expf(S1A[r]);
                e1B[r] = __expf(S1B[r]);
                e2A[r] = __expf(S2A[r]);
                e2B[r] = __expf(S2B[r]);
            }
            s1t[s] += (e1A[0] + e1A[1] + e1A[2] + e1A[3]) + (e1B[0] + e1B[1] + e1B[2] + e1B[3]);
            s2t[s] += (e2A[0] + e2A[1] + e2A[2] + e2A[3]) + (e2B[0] + e2B[1] + e2B[2] + e2B[3]);

            float pA0 = e1A[0], pA1 = pA0 + e1A[1], pA2 = pA1 + e1A[2], pA3 = pA2 + e1A[3];
            float Tn = __shfl_xor(pA3, 16);
            float pr = pA3 + Tn;
            float Tp = __shfl_xor(pr, 32);
            float baseA = carry[s] + ((qd & 1) ? Tn : 0.f) + ((qd & 2) ? Tp : 0.f);
            float cA0 = baseA + pA0, cA1 = baseA + pA1, cA2 = baseA + pA2, cA3 = baseA + pA3;
            carry[s] += pr + Tp;

            float pB0 = e1B[0], pB1 = pB0 + e1B[1], pB2 = pB1 + e1B[2], pB3 = pB2 + e1B[3];
            float TnB = __shfl_xor(pB3, 16);
            float prB = pB3 + TnB;
            float TpB = __shfl_xor(prB, 32);
            float baseB = carry[s] + ((qd & 1) ? TnB : 0.f) + ((qd & 2) ? TpB : 0.f);
            float cB0 = baseB + pB0, cB1 = baseB + pB1, cB2 = baseB + pB2, cB3 = baseB + pB3;
            carry[s] += prB + TpB;

            unsigned wA0 = pk2(e2A[0] * cA0, e2A[1] * cA1);
            unsigned wA1 = pk2(e2A[2] * cA2, e2A[3] * cA3);
            unsigned wB0 = pk2(e2B[0] * cB0, e2B[1] * cB1);
            unsigned wB1 = pk2(e2B[2] * cB2, e2B[3] * cB3);

            int sl1 = r16 + ((qd & 1) ? 32 : 0);
            int sl2 = sl1 + 16;
            int a0s1 = __shfl((int)wA0, sl1), a1s1 = __shfl((int)wA1, sl1);
            int b0s1 = __shfl((int)wB0, sl1), b1s1 = __shfl((int)wB1, sl1);
            int a0s2 = __shfl((int)wA0, sl2), a1s2 = __shfl((int)wA1, sl2);
            int b0s2 = __shfl((int)wB0, sl2), b1s2 = __shfl((int)wB1, sl2);
            bool loq = (qd < 2);
            union { int i[4]; bf16x8 v; } pu;
            pu.i[0] = loq ? a0s1 : b0s1;
            pu.i[1] = loq ? a1s1 : b1s1;
            pu.i[2] = loq ? a0s2 : b0s2;
            pu.i[3] = loq ? a1s2 : b1s2;

            o[s][0] = __builtin_amdgcn_mfma_f32_16x16x32_bf16(vf0, pu.v, o[s][0], 0, 0, 0);
            o[s][1] = __builtin_amdgcn_mfma_f32_16x16x32_bf16(vf1, pu.v, o[s][1], 0, 0, 0);
        }
    }

    #pragma unroll
    for (int s = 0; s < 2; ++s) {
        float st1 = s1t[s] + __shfl_xor(s1t[s], 16);
        st1 += __shfl_xor(st1, 32);
        float st2 = s2t[s] + __shfl_xor(s2t[s], 16);
        st2 += __shfl_xor(st2, 32);
        float nm = 1.f / (st1 * st2);
        const int l = q0 + 16 * s + r16;
        unsigned short* op = ao + ((size_t)(b * Lsz) + l) * Dsz + h * DKs;
        #pragma unroll
        for (int dt = 0; dt < 2; ++dt) {
            f32x4 ov = o[s][dt];
            *(ushort4*)(op + 16 * dt + 4 * qd) =
                make_ushort4(bfbits(ov[0] * nm), bfbits(ov[1] * nm),
                             bfbits(ov[2] * nm), bfbits(ov[3] * nm));
        }
    }
}

extern "C" void kernel_launch(void* const* d_in, const int* in_sizes, int n_in,
                              void* d_out, int out_size, void* d_ws, size_t ws_size,
                              hipStream_t stream) {
    const float* Q   = (const float*)d_in[0];
    const float* Wq  = (const float*)d_in[1];
    const float* bq  = (const float*)d_in[2];
    const float* Wk  = (const float*)d_in[3];
    const float* bk  = (const float*)d_in[4];
    const float* Wv  = (const float*)d_in[5];
    const float* bv  = (const float*)d_in[6];
    const float* Wql = (const float*)d_in[7];
    const float* bql = (const float*)d_in[8];
    const float* Wkl = (const float*)d_in[9];
    const float* bkl = (const float*)d_in[10];
    const float* Wo  = (const float*)d_in[11];
    const float* bo  = (const float*)d_in[12];
    // d_in[13] = triu: unused — phi @ triu == inclusive cumsum(phi, axis=-1)

    const size_t PLANE = (size_t)Bsz * Hn * Lsz * DKs;   // 6291456
    unsigned short* Qbf  = (unsigned short*)d_ws;
    unsigned short* WT   = Qbf + PLANE;                  // 4 x 512*512
    unsigned short* q_p  = WT + 4 * 262144;
    unsigned short* k_p  = q_p + PLANE;
    unsigned short* qL_p = k_p + PLANE;
    unsigned short* kL_p = qL_p + PLANE;
    unsigned short* vT_p = kL_p + PLANE;
    unsigned short* ao   = vT_p + PLANE;                 // total ~90 MB

    convq_kernel<<<3072, 256, 0, stream>>>(Q, Qbf);
    wtrans_kernel<<<dim3(8, 8, 4), 256, 0, stream>>>(Wq, Wk, Wv, Wo, WT);
    mm_kernel<0><<<768, 256, 0, stream>>>(Qbf, WT + 0 * 262144, bq, q_p);
    mm_kernel<1><<<768, 256, 0, stream>>>(Qbf, WT + 1 * 262144, bk, k_p);
    mm_kernel<2><<<768, 256, 0, stream>>>(Qbf, WT + 2 * 262144, bv, vT_p);
    lproj_kernel<<<768, 256, 0, stream>>>(q_p, Wql, bql, qL_p, SCALEF);
    lproj_kernel<<<768, 256, 0, stream>>>(k_p, Wkl, bkl, kL_p, 1.f);
    attn_mfma<<<dim3(3, Hn, Bsz), 256, 0, stream>>>(q_p, k_p, qL_p, kL_p, vT_p, ao);
    mm_kernel<3><<<768, 256, 0, stream>>>(ao, WT + 3 * 262144, bo, d_out);
}